// Round 1
// baseline (1073.464 us; speedup 1.0000x reference)
//
#include <hip/hip_runtime.h>
#include <math.h>

// StrangeAttractor: B=524288 rows, E=128.
//   d2[b,j] = ||x_b||^2 - 2 x_b . c_j + ||c_j||^2
//   idx[b]  = argmin_j sqrt(max(d2,0))   (first-min, numpy semantics)
//   s = 0.1 * exp(-min_dist / (radii[idx] + 1e-8))
//   attracted[b,:] = x_b*(1-s) + c_idx*s
// Outputs concatenated in d_out: [B*E] attracted (f32) then [B] idx (stored
// as float; harness reads whole buffer as f32).

#define BATCH 524288
#define E 128

__global__ void csq_kernel(const float* __restrict__ c, float* __restrict__ csq) {
    int j = threadIdx.x;  // 128 threads, 1 block
    const float* cj = c + j * E;
    float a0 = 0.f, a1 = 0.f, a2 = 0.f, a3 = 0.f;
#pragma unroll
    for (int k = 0; k < E; k += 4) {
        a0 = fmaf(cj[k + 0], cj[k + 0], a0);
        a1 = fmaf(cj[k + 1], cj[k + 1], a1);
        a2 = fmaf(cj[k + 2], cj[k + 2], a2);
        a3 = fmaf(cj[k + 3], cj[k + 3], a3);
    }
    csq[j] = (a0 + a1) + (a2 + a3);
}

__global__ __launch_bounds__(256, 2) void attractor_kernel(
        const float* __restrict__ xin,
        const float* __restrict__ c,
        const float* __restrict__ radii,
        const float* __restrict__ csq,
        float* __restrict__ out_attr,
        float* __restrict__ out_idx) {
    const int row = blockIdx.x * blockDim.x + threadIdx.x;

    // ---- load my row into registers (32 x dwordx4) ----
    const float4* x4 = reinterpret_cast<const float4*>(xin + (size_t)row * E);
    float x[E];
#pragma unroll
    for (int k = 0; k < E / 4; ++k) {
        float4 v = x4[k];
        x[4 * k + 0] = v.x;
        x[4 * k + 1] = v.y;
        x[4 * k + 2] = v.z;
        x[4 * k + 3] = v.w;
    }

    // ---- ||x||^2 (error here shifts all d2 equally -> argmin-invariant) ----
    float s0 = 0.f, s1 = 0.f, s2 = 0.f, s3 = 0.f;
#pragma unroll
    for (int k = 0; k < E; k += 4) {
        s0 = fmaf(x[k + 0], x[k + 0], s0);
        s1 = fmaf(x[k + 1], x[k + 1], s1);
        s2 = fmaf(x[k + 2], x[k + 2], s2);
        s3 = fmaf(x[k + 3], x[k + 3], s3);
    }
    const float xsq = (s0 + s1) + (s2 + s3);

    // ---- distance + running argmin over 128 centers ----
    // Center elements are wave-uniform (depend only on j,k) -> scalar loads.
    float best_dist = 3.4e38f;
    int best_j = 0;
#pragma unroll 1
    for (int j = 0; j < E; ++j) {
        const float* cj = c + j * E;
        float a0 = 0.f, a1 = 0.f, a2 = 0.f, a3 = 0.f;
#pragma unroll
        for (int k = 0; k < E; k += 4) {
            a0 = fmaf(x[k + 0], cj[k + 0], a0);
            a1 = fmaf(x[k + 1], cj[k + 1], a1);
            a2 = fmaf(x[k + 2], cj[k + 2], a2);
            a3 = fmaf(x[k + 3], cj[k + 3], a3);
        }
        const float dot = (a0 + a1) + (a2 + a3);
        const float d2 = xsq - 2.0f * dot + csq[j];
        const float dist = sqrtf(fmaxf(d2, 0.0f));
        // strict < keeps the FIRST minimum (numpy argmin semantics)
        if (dist < best_dist) {
            best_dist = dist;
            best_j = j;
        }
    }

    // ---- epilogue: blend toward chosen center ----
    const float r = radii[best_j];
    const float strength = __expf(-best_dist / (r + 1e-8f));
    const float s = 0.1f * strength;
    const float oms = 1.0f - s;

    const float* cb = c + best_j * E;  // per-lane gather, 64 KB table (L1/L2 hot)
    float4* o4 = reinterpret_cast<float4*>(out_attr + (size_t)row * E);
#pragma unroll
    for (int k = 0; k < E / 4; ++k) {
        float4 v;
        v.x = x[4 * k + 0] * oms + cb[4 * k + 0] * s;
        v.y = x[4 * k + 1] * oms + cb[4 * k + 1] * s;
        v.z = x[4 * k + 2] * oms + cb[4 * k + 2] * s;
        v.w = x[4 * k + 3] * oms + cb[4 * k + 3] * s;
        o4[k] = v;
    }
    out_idx[row] = (float)best_j;
}

extern "C" void kernel_launch(void* const* d_in, const int* in_sizes, int n_in,
                              void* d_out, int out_size, void* d_ws, size_t ws_size,
                              hipStream_t stream) {
    const float* x     = (const float*)d_in[0];  // [B, E]
    const float* c     = (const float*)d_in[1];  // [E, E]
    const float* radii = (const float*)d_in[2];  // [E]

    float* out_attr = (float*)d_out;              // [B*E]
    float* out_idx  = (float*)d_out + (size_t)BATCH * E;  // [B] as float
    float* csq      = (float*)d_ws;               // [E]

    csq_kernel<<<1, E, 0, stream>>>(c, csq);
    attractor_kernel<<<BATCH / 256, 256, 0, stream>>>(x, c, radii, csq,
                                                      out_attr, out_idx);
}